// Round 19
// baseline (466.059 us; speedup 1.0000x reference)
//
#include <hip/hip_runtime.h>
#include <cstdint>
#include <cstddef>

typedef __attribute__((ext_vector_type(8))) short short8;
typedef __attribute__((ext_vector_type(4))) float f32x4;
typedef __attribute__((ext_vector_type(4))) unsigned short us4;

#define GAS(p) ((const __attribute__((address_space(1))) void*)(p))
#define LAS(p) ((__attribute__((address_space(3))) void*)(p))

__device__ __forceinline__ unsigned short f2bf(float f) {
  union { float f; unsigned u; } v; v.f = f;
  return (unsigned short)((v.u + 0x7fffu + ((v.u >> 16) & 1u)) >> 16);
}

// ---------- fp32 -> bf16 convert (x4 vectorized) ----------
__global__ __launch_bounds__(256) void cvt_kernel(const float* __restrict__ in,
                                                  unsigned short* __restrict__ out, int n4) {
  int i = blockIdx.x * 256 + threadIdx.x;
  if (i >= n4) return;
  f32x4 v = ((const f32x4*)in)[i];
  us4 o;
#pragma unroll
  for (int j = 0; j < 4; ++j) o[j] = f2bf(v[j]);
  ((us4*)out)[i] = o;
}

// ---------- LayerNorm: one wave per row of 768, bf16 out ----------
__global__ __launch_bounds__(256) void ln_kernel(const float* __restrict__ x,
                                                 const float* __restrict__ g,
                                                 const float* __restrict__ b,
                                                 unsigned short* __restrict__ out) {
  const int wave = threadIdx.x >> 6, lane = threadIdx.x & 63;
  const int row = blockIdx.x * 4 + wave;
  const float* xr = x + (size_t)row * 768;
  f32x4 v[3];
  float s = 0.f, sq = 0.f;
#pragma unroll
  for (int c = 0; c < 3; ++c) {
    v[c] = *(const f32x4*)(xr + c * 256 + lane * 4);
#pragma unroll
    for (int j = 0; j < 4; ++j) { s += v[c][j]; sq += v[c][j] * v[c][j]; }
  }
#pragma unroll
  for (int off = 32; off > 0; off >>= 1) { s += __shfl_xor(s, off); sq += __shfl_xor(sq, off); }
  const float mu = s * (1.f / 768.f);
  const float var = sq * (1.f / 768.f) - mu * mu;
  const float rs = rsqrtf(var + 1e-5f);
  unsigned short* orow = out + (size_t)row * 768;
#pragma unroll
  for (int c = 0; c < 3; ++c) {
    f32x4 gg = *(const f32x4*)(g + c * 256 + lane * 4);
    f32x4 bb = *(const f32x4*)(b + c * 256 + lane * 4);
    us4 o;
#pragma unroll
    for (int j = 0; j < 4; ++j) o[j] = f2bf((v[c][j] - mu) * rs * gg[j] + bb[j]);
    *(us4*)(orow + c * 256 + lane * 4) = o;
  }
}

// ---------- GEMM: C[M,NN] = A[M,K](bf16) @ W[NN,K]^T(bf16) ----------
// r15/r18 verified config: 16-wave (1024-thread) 256xBN tile, 4x4 wave grid,
// 64x(BN/4) per wave -> 4 waves/SIMD. BK=32, 4 LDS buffers, one counted vmcnt
// + one barrier per K-tile. BN=192 balances QKV/proj/FC2 grids; FC1 BN=256.
template <int EPI, int NN, int K, int BN>
__global__ __launch_bounds__(1024, 4) void gemmW(
    const unsigned short* __restrict__ A, const unsigned short* __restrict__ W,
    float* __restrict__ outF, const float* __restrict__ bias, const float* __restrict__ res,
    unsigned short* __restrict__ outU,
    unsigned short* __restrict__ q, unsigned short* __restrict__ kk, unsigned short* __restrict__ vt) {
  constexpr int NFR = BN / 64;               // n-frags per wave (4 or 3)
  constexpr int BW = BN >> 4;                // waves needed to stage B (16 or 12)
  __shared__ unsigned short As[4][8192];     // 256 rows x 64B
  __shared__ unsigned short Bs[4][BN * 32];  // BN rows x 64B
  const int tid = threadIdx.x;
  const int wave = tid >> 6, lane = tid & 63;
  const int lr = lane & 15, lg = lane >> 4;
  const int wr = wave >> 2, wc = wave & 3;
  constexpr int GX = NN / BN;
  constexpr int NWG = GX * 64;               // all instantiations % 8 == 0
  int id = blockIdx.y * GX + blockIdx.x;
  id = (id & 7) * (NWG / 8) + (id >> 3);     // bijective XCD swizzle
  const int row0 = (id / GX) * 256, col0 = (id % GX) * BN;
  f32x4 acc[4][NFR] = {};
  const int sc = ((tid & 3) ^ ((tid >> 3) & 3)) * 8;
  int br = tid >> 2; if (br >= BN) br -= BN; // B stage row (wrap for BN=192)
  const unsigned short* ag = A + (size_t)(row0 + (tid >> 2)) * K + sc;
  const unsigned short* bg = W + (size_t)(col0 + br) * K + sc;
  const int bwav = (wave < BW ? wave : wave - BW) * 512;
  const int rsw = (lg ^ ((lr >> 1) & 3)) << 4;
  constexpr int KT = K / 32;                 // 24 or 96 (divisible by 4)

#define STG(buf, t_)                                                                           \
  {                                                                                            \
    __builtin_amdgcn_global_load_lds(GAS(ag + (t_) * 32), LAS(&As[buf][wave * 512]), 16, 0, 0);\
    __builtin_amdgcn_global_load_lds(GAS(bg + (t_) * 32), LAS(&Bs[buf][bwav]), 16, 0, 0);      \
  }

#define TILE(buf, t_)                                                                          \
  {                                                                                            \
    if ((t_) < KT - 2)       { asm volatile("s_waitcnt vmcnt(4)" ::: "memory"); }              \
    else if ((t_) == KT - 2) { asm volatile("s_waitcnt vmcnt(2)" ::: "memory"); }              \
    else                     { asm volatile("s_waitcnt vmcnt(0)" ::: "memory"); }              \
    __builtin_amdgcn_s_barrier();                                                              \
    if ((t_) + 3 < KT) STG(((buf) + 3) & 3, (t_) + 3);                                         \
    const char* Ab = (const char*)&As[buf][0];                                                 \
    const char* Bb = (const char*)&Bs[buf][0];                                                 \
    short8 af[4], bfv[NFR];                                                                    \
    _Pragma("unroll")                                                                          \
    for (int m = 0; m < 4; ++m) {                                                              \
      const int arow = wr * 64 + m * 16 + lr;                                                  \
      af[m] = *(const short8*)(Ab + arow * 64 + rsw);                                          \
    }                                                                                          \
    _Pragma("unroll")                                                                          \
    for (int n = 0; n < NFR; ++n) {                                                            \
      const int brow = wc * (NFR * 16) + n * 16 + lr;                                          \
      bfv[n] = *(const short8*)(Bb + brow * 64 + rsw);                                         \
    }                                                                                          \
    __builtin_amdgcn_s_setprio(1);                                                             \
    _Pragma("unroll")                                                                          \
    for (int m = 0; m < 4; ++m)                                                                \
      _Pragma("unroll")                                                                        \
      for (int n = 0; n < NFR; ++n)                                                            \
        acc[m][n] = __builtin_amdgcn_mfma_f32_16x16x32_bf16(af[m], bfv[n], acc[m][n], 0, 0, 0);\
    __builtin_amdgcn_s_setprio(0);                                                             \
  }

  STG(0, 0);
  STG(1, 1);
  STG(2, 2);
  for (int tt = 0; tt < KT; tt += 4) {
    TILE(0, tt);
    TILE(1, tt + 1);
    TILE(2, tt + 2);
    TILE(3, tt + 3);
  }
#undef TILE
#undef STG

  if (EPI == 0) {
    const int s = (col0 >= 1536) ? 2 : (col0 >= 768 ? 1 : 0);
#pragma unroll
    for (int m = 0; m < 4; ++m)
#pragma unroll
      for (int n = 0; n < NFR; ++n) {
        const int gb = col0 - s * 768 + wc * (NFR * 16) + n * 16;
        const int hh = gb >> 6;
        const int d = (gb & 63) + lr;
        const int g0 = row0 + wr * 64 + m * 16 + lg * 4;
        const int bt = g0 >> 10, nt0 = g0 & 1023;
        const size_t bh = (size_t)(bt * 12 + hh);
        if (s == 2) {
          us4 o;
#pragma unroll
          for (int r = 0; r < 4; ++r) o[r] = f2bf(acc[m][n][r]);
          *(us4*)(vt + (bh * 64 + d) * 1024 + nt0) = o;
        } else {
#pragma unroll
          for (int r = 0; r < 4; ++r) {
            const float val = acc[m][n][r];
            // q prescaled by 0.125*log2e: softmax runs in exp2 domain
            if (s == 0) q[(bh * 1024 + nt0 + r) * 64 + d] = f2bf(val * 0.18033688f);
            else        kk[(bh * 1024 + nt0 + r) * 64 + d] = f2bf(val);
          }
        }
      }
  } else if (EPI == 1) {
#pragma unroll
    for (int m = 0; m < 4; ++m)
#pragma unroll
      for (int n = 0; n < NFR; ++n) {
        const int gcol = col0 + wc * (NFR * 16) + n * 16 + lr;
        const float bn = bias[gcol];
#pragma unroll
        for (int r = 0; r < 4; ++r) {
          const int grow = row0 + wr * 64 + m * 16 + lg * 4 + r;
          const size_t idx = (size_t)grow * NN + gcol;
          outF[idx] = acc[m][n][r] + bn + res[idx];
        }
      }
  } else {
#pragma unroll
    for (int m = 0; m < 4; ++m)
#pragma unroll
      for (int n = 0; n < NFR; ++n) {
        const int gcol = col0 + wc * (NFR * 16) + n * 16 + lr;
        const float bn = bias[gcol];
#pragma unroll
        for (int r = 0; r < 4; ++r) {
          const int grow = row0 + wr * 64 + m * 16 + lg * 4 + r;
          const size_t idx = (size_t)grow * NN + gcol;
          const float t = acc[m][n][r] + bn;
          const float u = t * (1.59576912f + t * t * 0.07135481f);
          const float eu = __expf(-u);
          outU[idx] = f2bf(t / (1.f + eu));
        }
      }
  }
}

// ---------- Flash attention, swapped-operand (S^T / O^T) ----------
// r19: 512-thread blocks (8 waves x 32 q-rows = 256 q/block) -> LDS 64 KB ->
// 2 blocks/CU = 16 waves/CU (up from 12): more TLP to hide the trans-pipe
// (exp2) and LDS latency that pins this kernel. Staging: 512 threads cover a
// full 64x128B tile in ONE issue per buffer (2/tile, vmcnt 2/0). Keeps r15
// fixed-shift exp2 softmax + ones-MFMA denominator + per-wave LDS P-buffer +
// head-clustered XCD remap (qt=(id>>3)&3, head=(id&7)+8*(id>>5)).
__global__ __launch_bounds__(512, 4) void attn_kernel(
    const unsigned short* __restrict__ Q, const unsigned short* __restrict__ K,
    const unsigned short* __restrict__ V, unsigned short* __restrict__ O) {
  __shared__ unsigned short Ks[2][64 * 64];
  __shared__ unsigned short Vs[2][64 * 64];
  __shared__ unsigned short Ps[8][32 * 64];   // per-wave P, swizzled 128B rows
  const int tid = threadIdx.x, wave = tid >> 6, lane = tid & 63;
  const int lr = lane & 15, lg = lane >> 4;
  const int id = blockIdx.x;
  const int qt = (id >> 3) & 3;
  const int head = (id & 7) + 8 * (id >> 5);   // xcd + 8*hx, 0..191
  const int hh = head % 12, bb = head / 12;
  const size_t bh = (size_t)bb * 12 + hh;
  const unsigned short* Qg = Q + bh * 1024 * 64;
  const unsigned short* Kg = K + bh * 1024 * 64;
  const unsigned short* Vg = V + bh * 64 * 1024;
  const int q0 = qt * 256 + wave * 32;
  short8 aq[2][2];  // [nq][kb], Q prescaled by 0.125*log2e
#pragma unroll
  for (int nq = 0; nq < 2; ++nq)
#pragma unroll
    for (int kb = 0; kb < 2; ++kb)
      aq[nq][kb] = *(const short8*)(Qg + (size_t)(q0 + nq * 16 + lr) * 64 + kb * 32 + lg * 8);
  f32x4 oacc[4][2] = {};  // [mb over d][nq], O^T: col=q(lr), row=d
  f32x4 accl[2] = {};     // softmax denominator via ones-MFMA
  short8 vones;
#pragma unroll
  for (int j = 0; j < 8; ++j) vones[j] = (short)0x3F80;  // bf16 1.0
  const int srow = tid >> 3;                               // 0..63: full tile, one issue
  const int sswz = (((tid & 7) * 16) ^ ((srow & 7) << 4)) >> 1;
  char* Pw = (char*)&Ps[wave][0];

#define ATTN_STAGE(buf, t_)                                                                      \
  {                                                                                              \
    const int kv_ = (t_) * 64;                                                                   \
    __builtin_amdgcn_global_load_lds(GAS(Kg + (size_t)(kv_ + srow) * 64 + sswz),                 \
                                     LAS(&Ks[buf][(tid >> 6) * 512]), 16, 0, 0);                 \
    __builtin_amdgcn_global_load_lds(GAS(Vg + (size_t)srow * 1024 + kv_ + sswz),                 \
                                     LAS(&Vs[buf][(tid >> 6) * 512]), 16, 0, 0);                 \
  }

#define ATILE(cur, t_)                                                                           \
  {                                                                                              \
    if ((t_) < 15) { asm volatile("s_waitcnt vmcnt(2)" ::: "memory"); }                          \
    else           { asm volatile("s_waitcnt vmcnt(0)" ::: "memory"); }                          \
    __builtin_amdgcn_s_barrier();                                                                \
    __builtin_amdgcn_sched_barrier(0);                                                           \
    f32x4 sacc[4][2] = {};                                                                       \
    _Pragma("unroll")                                                                            \
    for (int kb = 0; kb < 2; ++kb) {                                                             \
      short8 kf[4];                                                                              \
      _Pragma("unroll")                                                                          \
      for (int mk = 0; mk < 4; ++mk) {                                                           \
        const int row = mk * 16 + lr;                                                            \
        const int boff = row * 128 + ((kb * 64 + lg * 16) ^ ((row & 7) << 4));                   \
        kf[mk] = *(const short8*)((const char*)&Ks[cur][0] + boff);                              \
      }                                                                                          \
      _Pragma("unroll")                                                                          \
      for (int mk = 0; mk < 4; ++mk)                                                             \
        _Pragma("unroll")                                                                        \
        for (int nq = 0; nq < 2; ++nq)                                                           \
          sacc[mk][nq] = __builtin_amdgcn_mfma_f32_16x16x32_bf16(kf[mk], aq[nq][kb], sacc[mk][nq], 0, 0, 0); \
    }                                                                                            \
    _Pragma("unroll")                                                                            \
    for (int nq = 0; nq < 2; ++nq) {                                                             \
      const int prow = nq * 16 + lr;                                                             \
      _Pragma("unroll")                                                                          \
      for (int mk = 0; mk < 4; ++mk) {                                                           \
        unsigned p0, p1;                                                                         \
        const float e0 = exp2f(sacc[mk][nq][0]);                                                 \
        const float e1 = exp2f(sacc[mk][nq][1]);                                                 \
        const float e2 = exp2f(sacc[mk][nq][2]);                                                 \
        const float e3 = exp2f(sacc[mk][nq][3]);                                                 \
        asm("v_cvt_pk_bf16_f32 %0, %1, %2" : "=v"(p0) : "v"(e0), "v"(e1));                       \
        asm("v_cvt_pk_bf16_f32 %0, %1, %2" : "=v"(p1) : "v"(e2), "v"(e3));                       \
        uint2 w; w.x = p0; w.y = p1;                                                             \
        *(uint2*)(Pw + prow * 128 + ((mk * 32 + lg * 8) ^ ((lr & 7) << 4))) = w;                 \
      }                                                                                          \
    }                                                                                            \
    _Pragma("unroll")                                                                            \
    for (int kb = 0; kb < 2; ++kb) {                                                             \
      short8 vf[4];                                                                              \
      _Pragma("unroll")                                                                          \
      for (int mb = 0; mb < 4; ++mb) {                                                           \
        const int row = mb * 16 + lr;                                                            \
        const int boff = row * 128 + ((kb * 64 + lg * 16) ^ ((row & 7) << 4));                   \
        vf[mb] = *(const short8*)((const char*)&Vs[cur][0] + boff);                              \
      }                                                                                          \
      _Pragma("unroll")                                                                          \
      for (int nq = 0; nq < 2; ++nq) {                                                           \
        const int prow = nq * 16 + lr;                                                           \
        const short8 pb = *(const short8*)(Pw + prow * 128 + ((kb * 64 + lg * 16) ^ ((lr & 7) << 4))); \
        accl[nq] = __builtin_amdgcn_mfma_f32_16x16x32_bf16(vones, pb, accl[nq], 0, 0, 0);        \
        _Pragma("unroll")                                                                        \
        for (int mb = 0; mb < 4; ++mb)                                                           \
          oacc[mb][nq] = __builtin_amdgcn_mfma_f32_16x16x32_bf16(vf[mb], pb, oacc[mb][nq], 0, 0, 0); \
      }                                                                                          \
    }                                                                                            \
    asm volatile("s_waitcnt lgkmcnt(0)" ::: "memory");                                           \
    __builtin_amdgcn_sched_barrier(0);                                                           \
    __builtin_amdgcn_s_barrier();                                                                \
    if ((t_) + 2 < 16) ATTN_STAGE(cur, (t_) + 2);                                                \
  }

  ATTN_STAGE(0, 0);
  ATTN_STAGE(1, 1);
  for (int tt = 0; tt < 8; ++tt) {
    ATILE(0, 2 * tt)
    ATILE(1, 2 * tt + 1)
  }
#undef ATILE
#undef ATTN_STAGE
#pragma unroll
  for (int nq = 0; nq < 2; ++nq) {
    const float linv = 1.f / accl[nq][0];
    const size_t tok = (size_t)(bb << 10) + q0 + nq * 16 + lr;
#pragma unroll
    for (int mb = 0; mb < 4; ++mb) {
      us4 o;
#pragma unroll
      for (int r = 0; r < 4; ++r) o[r] = f2bf(oacc[mb][nq][r] * linv);
      *(us4*)(O + tok * 768 + hh * 64 + mb * 16 + lg * 4) = o;
    }
  }
}

extern "C" void kernel_launch(void* const* d_in, const int* in_sizes, int n_in,
                              void* d_out, int out_size, void* d_ws, size_t ws_size,
                              hipStream_t stream) {
  const float* x      = (const float*)d_in[0];
  const float* ln1_g  = (const float*)d_in[1];
  const float* ln1_b  = (const float*)d_in[2];
  const float* qkv_w  = (const float*)d_in[3];
  const float* proj_w = (const float*)d_in[4];
  const float* proj_b = (const float*)d_in[5];
  const float* ln2_g  = (const float*)d_in[6];
  const float* ln2_b  = (const float*)d_in[7];
  const float* fc1_w  = (const float*)d_in[8];
  const float* fc1_b  = (const float*)d_in[9];
  const float* fc2_w  = (const float*)d_in[10];
  const float* fc2_b  = (const float*)d_in[11];
  float* out = (float*)d_out;
  char* ws = (char*)d_ws;

  unsigned short* wqkv = (unsigned short*)(ws + 0);
  unsigned short* wproj = (unsigned short*)(ws + 3538944);
  unsigned short* wfc1 = (unsigned short*)(ws + 4718592);
  unsigned short* wfc2 = (unsigned short*)(ws + 9437184);
  unsigned short* hbuf = (unsigned short*)(ws + 14155776);          // 16384x768 bf16
  char* big = ws + 39321600;                                        // 96 MB region
  unsigned short* qb  = (unsigned short*)(big);
  unsigned short* kb  = (unsigned short*)(big + 25165824);
  unsigned short* vtb = (unsigned short*)(big + 50331648);
  unsigned short* ob  = (unsigned short*)(big + 75497472);
  unsigned short* hid = (unsigned short*)(big);                     // reuses q/k/vt/o after attn+proj

  // weights -> bf16
  cvt_kernel<<<1728, 256, 0, stream>>>(qkv_w, wqkv, 442368);
  cvt_kernel<<<576, 256, 0, stream>>>(proj_w, wproj, 147456);
  cvt_kernel<<<2304, 256, 0, stream>>>(fc1_w, wfc1, 589824);
  cvt_kernel<<<2304, 256, 0, stream>>>(fc2_w, wfc2, 589824);

  // LN1
  ln_kernel<<<4096, 256, 0, stream>>>(x, ln1_g, ln1_b, hbuf);
  // QKV (BN=192: 768 blocks = 3/CU exact)
  gemmW<0, 2304, 768, 192><<<dim3(12, 64), 1024, 0, stream>>>(
      hbuf, wqkv, nullptr, nullptr, nullptr, nullptr, qb, kb, vtb);
  // attention (512-thread blocks, 256 q-rows each; head-clustered XCD remap)
  attn_kernel<<<dim3(768), 512, 0, stream>>>(qb, kb, vtb, ob);
  // proj + residual -> x1 (in d_out)  (BN=192: 256 blocks = 1/CU exact)
  gemmW<1, 768, 768, 192><<<dim3(4, 64), 1024, 0, stream>>>(
      ob, wproj, out, proj_b, x, nullptr, nullptr, nullptr, nullptr);
  // LN2
  ln_kernel<<<4096, 256, 0, stream>>>(out, ln2_g, ln2_b, hbuf);
  // FC1 + gelu (BN=256: 768 blocks = 3/CU exact)
  gemmW<2, 3072, 768, 256><<<dim3(12, 64), 1024, 0, stream>>>(
      hbuf, wfc1, nullptr, fc1_b, nullptr, hid, nullptr, nullptr, nullptr);
  // FC2 + residual -> out (BN=192: 256 blocks = 1/CU exact)
  gemmW<1, 768, 3072, 192><<<dim3(4, 64), 1024, 0, stream>>>(
      hid, wfc2, out, fc2_b, out, nullptr, nullptr, nullptr, nullptr);
}

// Round 20
// 441.159 us; speedup vs baseline: 1.0564x; 1.0564x over previous
//
#include <hip/hip_runtime.h>
#include <cstdint>
#include <cstddef>

typedef __attribute__((ext_vector_type(8))) short short8;
typedef __attribute__((ext_vector_type(4))) float f32x4;
typedef __attribute__((ext_vector_type(4))) unsigned short us4;

#define GAS(p) ((const __attribute__((address_space(1))) void*)(p))
#define LAS(p) ((__attribute__((address_space(3))) void*)(p))

__device__ __forceinline__ unsigned short f2bf(float f) {
  union { float f; unsigned u; } v; v.f = f;
  return (unsigned short)((v.u + 0x7fffu + ((v.u >> 16) & 1u)) >> 16);
}

// ---------- fp32 -> bf16 convert (x4 vectorized) ----------
__global__ __launch_bounds__(256) void cvt_kernel(const float* __restrict__ in,
                                                  unsigned short* __restrict__ out, int n4) {
  int i = blockIdx.x * 256 + threadIdx.x;
  if (i >= n4) return;
  f32x4 v = ((const f32x4*)in)[i];
  us4 o;
#pragma unroll
  for (int j = 0; j < 4; ++j) o[j] = f2bf(v[j]);
  ((us4*)out)[i] = o;
}

// ---------- LayerNorm: one wave per row of 768, bf16 out ----------
__global__ __launch_bounds__(256) void ln_kernel(const float* __restrict__ x,
                                                 const float* __restrict__ g,
                                                 const float* __restrict__ b,
                                                 unsigned short* __restrict__ out) {
  const int wave = threadIdx.x >> 6, lane = threadIdx.x & 63;
  const int row = blockIdx.x * 4 + wave;
  const float* xr = x + (size_t)row * 768;
  f32x4 v[3];
  float s = 0.f, sq = 0.f;
#pragma unroll
  for (int c = 0; c < 3; ++c) {
    v[c] = *(const f32x4*)(xr + c * 256 + lane * 4);
#pragma unroll
    for (int j = 0; j < 4; ++j) { s += v[c][j]; sq += v[c][j] * v[c][j]; }
  }
#pragma unroll
  for (int off = 32; off > 0; off >>= 1) { s += __shfl_xor(s, off); sq += __shfl_xor(sq, off); }
  const float mu = s * (1.f / 768.f);
  const float var = sq * (1.f / 768.f) - mu * mu;
  const float rs = rsqrtf(var + 1e-5f);
  unsigned short* orow = out + (size_t)row * 768;
#pragma unroll
  for (int c = 0; c < 3; ++c) {
    f32x4 gg = *(const f32x4*)(g + c * 256 + lane * 4);
    f32x4 bb = *(const f32x4*)(b + c * 256 + lane * 4);
    us4 o;
#pragma unroll
    for (int j = 0; j < 4; ++j) o[j] = f2bf((v[c][j] - mu) * rs * gg[j] + bb[j]);
    *(us4*)(orow + c * 256 + lane * 4) = o;
  }
}

// ---------- GEMM: C[M,NN] = A[M,K](bf16) @ W[NN,K]^T(bf16) ----------
// Final config (best measured, reproduced at 442-443 us): 16-wave
// (1024-thread) 256xBN tile, 4x4 wave grid, 64x(BN/4) per wave -> 4
// waves/SIMD (r11 lever; r17 confirmed vs 2x512-thread blocks). BK=32, 4 LDS
// buffers, one counted vmcnt + one barrier per K-tile (publish rule r9).
// BN=192 balances QKV/proj/FC2 grids to exact CU multiples; FC1 BN=256.
// Verified 0-conflict XOR swizzle; bijective XCD block swizzle.
template <int EPI, int NN, int K, int BN>
__global__ __launch_bounds__(1024, 4) void gemmW(
    const unsigned short* __restrict__ A, const unsigned short* __restrict__ W,
    float* __restrict__ outF, const float* __restrict__ bias, const float* __restrict__ res,
    unsigned short* __restrict__ outU,
    unsigned short* __restrict__ q, unsigned short* __restrict__ kk, unsigned short* __restrict__ vt) {
  constexpr int NFR = BN / 64;               // n-frags per wave (4 or 3)
  constexpr int BW = BN >> 4;                // waves needed to stage B (16 or 12)
  __shared__ unsigned short As[4][8192];     // 256 rows x 64B
  __shared__ unsigned short Bs[4][BN * 32];  // BN rows x 64B
  const int tid = threadIdx.x;
  const int wave = tid >> 6, lane = tid & 63;
  const int lr = lane & 15, lg = lane >> 4;
  const int wr = wave >> 2, wc = wave & 3;
  constexpr int GX = NN / BN;
  constexpr int NWG = GX * 64;               // all instantiations % 8 == 0
  int id = blockIdx.y * GX + blockIdx.x;
  id = (id & 7) * (NWG / 8) + (id >> 3);     // bijective XCD swizzle
  const int row0 = (id / GX) * 256, col0 = (id % GX) * BN;
  f32x4 acc[4][NFR] = {};
  const int sc = ((tid & 3) ^ ((tid >> 3) & 3)) * 8;
  int br = tid >> 2; if (br >= BN) br -= BN; // B stage row (wrap for BN=192)
  const unsigned short* ag = A + (size_t)(row0 + (tid >> 2)) * K + sc;
  const unsigned short* bg = W + (size_t)(col0 + br) * K + sc;
  const int bwav = (wave < BW ? wave : wave - BW) * 512;
  const int rsw = (lg ^ ((lr >> 1) & 3)) << 4;
  constexpr int KT = K / 32;                 // 24 or 96 (divisible by 4)

#define STG(buf, t_)                                                                           \
  {                                                                                            \
    __builtin_amdgcn_global_load_lds(GAS(ag + (t_) * 32), LAS(&As[buf][wave * 512]), 16, 0, 0);\
    __builtin_amdgcn_global_load_lds(GAS(bg + (t_) * 32), LAS(&Bs[buf][bwav]), 16, 0, 0);      \
  }

#define TILE(buf, t_)                                                                          \
  {                                                                                            \
    if ((t_) < KT - 2)       { asm volatile("s_waitcnt vmcnt(4)" ::: "memory"); }              \
    else if ((t_) == KT - 2) { asm volatile("s_waitcnt vmcnt(2)" ::: "memory"); }              \
    else                     { asm volatile("s_waitcnt vmcnt(0)" ::: "memory"); }              \
    __builtin_amdgcn_s_barrier();                                                              \
    if ((t_) + 3 < KT) STG(((buf) + 3) & 3, (t_) + 3);                                         \
    const char* Ab = (const char*)&As[buf][0];                                                 \
    const char* Bb = (const char*)&Bs[buf][0];                                                 \
    short8 af[4], bfv[NFR];                                                                    \
    _Pragma("unroll")                                                                          \
    for (int m = 0; m < 4; ++m) {                                                              \
      const int arow = wr * 64 + m * 16 + lr;                                                  \
      af[m] = *(const short8*)(Ab + arow * 64 + rsw);                                          \
    }                                                                                          \
    _Pragma("unroll")                                                                          \
    for (int n = 0; n < NFR; ++n) {                                                            \
      const int brow = wc * (NFR * 16) + n * 16 + lr;                                          \
      bfv[n] = *(const short8*)(Bb + brow * 64 + rsw);                                         \
    }                                                                                          \
    __builtin_amdgcn_s_setprio(1);                                                             \
    _Pragma("unroll")                                                                          \
    for (int m = 0; m < 4; ++m)                                                                \
      _Pragma("unroll")                                                                        \
      for (int n = 0; n < NFR; ++n)                                                            \
        acc[m][n] = __builtin_amdgcn_mfma_f32_16x16x32_bf16(af[m], bfv[n], acc[m][n], 0, 0, 0);\
    __builtin_amdgcn_s_setprio(0);                                                             \
  }

  STG(0, 0);
  STG(1, 1);
  STG(2, 2);
  for (int tt = 0; tt < KT; tt += 4) {
    TILE(0, tt);
    TILE(1, tt + 1);
    TILE(2, tt + 2);
    TILE(3, tt + 3);
  }
#undef TILE
#undef STG

  if (EPI == 0) {
    const int s = (col0 >= 1536) ? 2 : (col0 >= 768 ? 1 : 0);
#pragma unroll
    for (int m = 0; m < 4; ++m)
#pragma unroll
      for (int n = 0; n < NFR; ++n) {
        const int gb = col0 - s * 768 + wc * (NFR * 16) + n * 16;
        const int hh = gb >> 6;
        const int d = (gb & 63) + lr;
        const int g0 = row0 + wr * 64 + m * 16 + lg * 4;
        const int bt = g0 >> 10, nt0 = g0 & 1023;
        const size_t bh = (size_t)(bt * 12 + hh);
        if (s == 2) {
          us4 o;
#pragma unroll
          for (int r = 0; r < 4; ++r) o[r] = f2bf(acc[m][n][r]);
          *(us4*)(vt + (bh * 64 + d) * 1024 + nt0) = o;
        } else {
#pragma unroll
          for (int r = 0; r < 4; ++r) {
            const float val = acc[m][n][r];
            // q prescaled by 0.125*log2e: softmax runs in exp2 domain
            if (s == 0) q[(bh * 1024 + nt0 + r) * 64 + d] = f2bf(val * 0.18033688f);
            else        kk[(bh * 1024 + nt0 + r) * 64 + d] = f2bf(val);
          }
        }
      }
  } else if (EPI == 1) {
#pragma unroll
    for (int m = 0; m < 4; ++m)
#pragma unroll
      for (int n = 0; n < NFR; ++n) {
        const int gcol = col0 + wc * (NFR * 16) + n * 16 + lr;
        const float bn = bias[gcol];
#pragma unroll
        for (int r = 0; r < 4; ++r) {
          const int grow = row0 + wr * 64 + m * 16 + lg * 4 + r;
          const size_t idx = (size_t)grow * NN + gcol;
          outF[idx] = acc[m][n][r] + bn + res[idx];
        }
      }
  } else {
#pragma unroll
    for (int m = 0; m < 4; ++m)
#pragma unroll
      for (int n = 0; n < NFR; ++n) {
        const int gcol = col0 + wc * (NFR * 16) + n * 16 + lr;
        const float bn = bias[gcol];
#pragma unroll
        for (int r = 0; r < 4; ++r) {
          const int grow = row0 + wr * 64 + m * 16 + lg * 4 + r;
          const size_t idx = (size_t)grow * NN + gcol;
          const float t = acc[m][n][r] + bn;
          const float u = t * (1.59576912f + t * t * 0.07135481f);
          const float eu = __expf(-u);
          outU[idx] = f2bf(t / (1.f + eu));
        }
      }
  }
}

// ---------- Flash attention, swapped-operand (S^T / O^T) ----------
// Final config (r15, best measured): 256-thread blocks, 4 waves x 32 q-rows;
// fixed-shift softmax (m=0, exp2 domain, bounded scores), ones-MFMA
// denominator, per-wave LDS P-buffer, head-clustered XCD remap (FETCH
// 209->37 MB). r19 showed 512-thread variant trades L2 locality for nothing.
__global__ __launch_bounds__(256) void attn_kernel(
    const unsigned short* __restrict__ Q, const unsigned short* __restrict__ K,
    const unsigned short* __restrict__ V, unsigned short* __restrict__ O) {
  __shared__ unsigned short Ks[2][64 * 64];
  __shared__ unsigned short Vs[2][64 * 64];
  __shared__ unsigned short Ps[4][32 * 64];   // per-wave P, swizzled 128B rows
  const int tid = threadIdx.x, wave = tid >> 6, lane = tid & 63;
  const int lr = lane & 15, lg = lane >> 4;
  const int id = blockIdx.x;
  const int qt = (id >> 3) & 7;
  const int head = (id & 7) + 8 * (id >> 6);   // xcd + 8*hx, 0..191
  const int hh = head % 12, bb = head / 12;
  const size_t bh = (size_t)bb * 12 + hh;
  const unsigned short* Qg = Q + bh * 1024 * 64;
  const unsigned short* Kg = K + bh * 1024 * 64;
  const unsigned short* Vg = V + bh * 64 * 1024;
  const int q0 = qt * 128 + wave * 32;
  short8 aq[2][2];  // [nq][kb], Q prescaled by 0.125*log2e
#pragma unroll
  for (int nq = 0; nq < 2; ++nq)
#pragma unroll
    for (int kb = 0; kb < 2; ++kb)
      aq[nq][kb] = *(const short8*)(Qg + (size_t)(q0 + nq * 16 + lr) * 64 + kb * 32 + lg * 8);
  f32x4 oacc[4][2] = {};  // [mb over d][nq], O^T: col=q(lr), row=d
  f32x4 accl[2] = {};     // softmax denominator via ones-MFMA
  short8 vones;
#pragma unroll
  for (int j = 0; j < 8; ++j) vones[j] = (short)0x3F80;  // bf16 1.0
  const int srow = tid >> 3;
  const int sswz = (((tid & 7) * 16) ^ ((srow & 7) << 4)) >> 1;
  char* Pw = (char*)&Ps[wave][0];

#define ATTN_STAGE(buf, t_)                                                                      \
  {                                                                                              \
    const int kv_ = (t_) * 64;                                                                   \
    _Pragma("unroll")                                                                            \
    for (int is = 0; is < 2; ++is) {                                                             \
      __builtin_amdgcn_global_load_lds(GAS(Kg + (size_t)(kv_ + is * 32 + srow) * 64 + sswz),     \
                                       LAS(&Ks[buf][is * 2048 + wave * 512]), 16, 0, 0);         \
      __builtin_amdgcn_global_load_lds(GAS(Vg + (size_t)(is * 32 + srow) * 1024 + kv_ + sswz),   \
                                       LAS(&Vs[buf][is * 2048 + wave * 512]), 16, 0, 0);         \
    }                                                                                            \
  }

#define ATILE(cur, t_)                                                                           \
  {                                                                                              \
    if ((t_) < 15) { asm volatile("s_waitcnt vmcnt(4)" ::: "memory"); }                          \
    else           { asm volatile("s_waitcnt vmcnt(0)" ::: "memory"); }                          \
    __builtin_amdgcn_s_barrier();                                                                \
    __builtin_amdgcn_sched_barrier(0);                                                           \
    f32x4 sacc[4][2] = {};                                                                       \
    _Pragma("unroll")                                                                            \
    for (int kb = 0; kb < 2; ++kb) {                                                             \
      short8 kf[4];                                                                              \
      _Pragma("unroll")                                                                          \
      for (int mk = 0; mk < 4; ++mk) {                                                           \
        const int row = mk * 16 + lr;                                                            \
        const int boff = row * 128 + ((kb * 64 + lg * 16) ^ ((row & 7) << 4));                   \
        kf[mk] = *(const short8*)((const char*)&Ks[cur][0] + boff);                              \
      }                                                                                          \
      _Pragma("unroll")                                                                          \
      for (int mk = 0; mk < 4; ++mk)                                                             \
        _Pragma("unroll")                                                                        \
        for (int nq = 0; nq < 2; ++nq)                                                           \
          sacc[mk][nq] = __builtin_amdgcn_mfma_f32_16x16x32_bf16(kf[mk], aq[nq][kb], sacc[mk][nq], 0, 0, 0); \
    }                                                                                            \
    _Pragma("unroll")                                                                            \
    for (int nq = 0; nq < 2; ++nq) {                                                             \
      const int prow = nq * 16 + lr;                                                             \
      _Pragma("unroll")                                                                          \
      for (int mk = 0; mk < 4; ++mk) {                                                           \
        unsigned p0, p1;                                                                         \
        const float e0 = exp2f(sacc[mk][nq][0]);                                                 \
        const float e1 = exp2f(sacc[mk][nq][1]);                                                 \
        const float e2 = exp2f(sacc[mk][nq][2]);                                                 \
        const float e3 = exp2f(sacc[mk][nq][3]);                                                 \
        asm("v_cvt_pk_bf16_f32 %0, %1, %2" : "=v"(p0) : "v"(e0), "v"(e1));                       \
        asm("v_cvt_pk_bf16_f32 %0, %1, %2" : "=v"(p1) : "v"(e2), "v"(e3));                       \
        uint2 w; w.x = p0; w.y = p1;                                                             \
        *(uint2*)(Pw + prow * 128 + ((mk * 32 + lg * 8) ^ ((lr & 7) << 4))) = w;                 \
      }                                                                                          \
    }                                                                                            \
    _Pragma("unroll")                                                                            \
    for (int kb = 0; kb < 2; ++kb) {                                                             \
      short8 vf[4];                                                                              \
      _Pragma("unroll")                                                                          \
      for (int mb = 0; mb < 4; ++mb) {                                                           \
        const int row = mb * 16 + lr;                                                            \
        const int boff = row * 128 + ((kb * 64 + lg * 16) ^ ((row & 7) << 4));                   \
        vf[mb] = *(const short8*)((const char*)&Vs[cur][0] + boff);                              \
      }                                                                                          \
      _Pragma("unroll")                                                                          \
      for (int nq = 0; nq < 2; ++nq) {                                                           \
        const int prow = nq * 16 + lr;                                                           \
        const short8 pb = *(const short8*)(Pw + prow * 128 + ((kb * 64 + lg * 16) ^ ((lr & 7) << 4))); \
        accl[nq] = __builtin_amdgcn_mfma_f32_16x16x32_bf16(vones, pb, accl[nq], 0, 0, 0);        \
        _Pragma("unroll")                                                                        \
        for (int mb = 0; mb < 4; ++mb)                                                           \
          oacc[mb][nq] = __builtin_amdgcn_mfma_f32_16x16x32_bf16(vf[mb], pb, oacc[mb][nq], 0, 0, 0); \
      }                                                                                          \
    }                                                                                            \
    asm volatile("s_waitcnt lgkmcnt(0)" ::: "memory");                                           \
    __builtin_amdgcn_sched_barrier(0);                                                           \
    __builtin_amdgcn_s_barrier();                                                                \
    if ((t_) + 2 < 16) ATTN_STAGE(cur, (t_) + 2);                                                \
  }

  ATTN_STAGE(0, 0);
  ATTN_STAGE(1, 1);
  for (int tt = 0; tt < 8; ++tt) {
    ATILE(0, 2 * tt)
    ATILE(1, 2 * tt + 1)
  }
#undef ATILE
#undef ATTN_STAGE
#pragma unroll
  for (int nq = 0; nq < 2; ++nq) {
    const float linv = 1.f / accl[nq][0];
    const size_t tok = (size_t)(bb << 10) + q0 + nq * 16 + lr;
#pragma unroll
    for (int mb = 0; mb < 4; ++mb) {
      us4 o;
#pragma unroll
      for (int r = 0; r < 4; ++r) o[r] = f2bf(oacc[mb][nq][r] * linv);
      *(us4*)(O + tok * 768 + hh * 64 + mb * 16 + lg * 4) = o;
    }
  }
}

extern "C" void kernel_launch(void* const* d_in, const int* in_sizes, int n_in,
                              void* d_out, int out_size, void* d_ws, size_t ws_size,
                              hipStream_t stream) {
  const float* x      = (const float*)d_in[0];
  const float* ln1_g  = (const float*)d_in[1];
  const float* ln1_b  = (const float*)d_in[2];
  const float* qkv_w  = (const float*)d_in[3];
  const float* proj_w = (const float*)d_in[4];
  const float* proj_b = (const float*)d_in[5];
  const float* ln2_g  = (const float*)d_in[6];
  const float* ln2_b  = (const float*)d_in[7];
  const float* fc1_w  = (const float*)d_in[8];
  const float* fc1_b  = (const float*)d_in[9];
  const float* fc2_w  = (const float*)d_in[10];
  const float* fc2_b  = (const float*)d_in[11];
  float* out = (float*)d_out;
  char* ws = (char*)d_ws;

  unsigned short* wqkv = (unsigned short*)(ws + 0);
  unsigned short* wproj = (unsigned short*)(ws + 3538944);
  unsigned short* wfc1 = (unsigned short*)(ws + 4718592);
  unsigned short* wfc2 = (unsigned short*)(ws + 9437184);
  unsigned short* hbuf = (unsigned short*)(ws + 14155776);          // 16384x768 bf16
  char* big = ws + 39321600;                                        // 96 MB region
  unsigned short* qb  = (unsigned short*)(big);
  unsigned short* kb  = (unsigned short*)(big + 25165824);
  unsigned short* vtb = (unsigned short*)(big + 50331648);
  unsigned short* ob  = (unsigned short*)(big + 75497472);
  unsigned short* hid = (unsigned short*)(big);                     // reuses q/k/vt/o after attn+proj

  // weights -> bf16
  cvt_kernel<<<1728, 256, 0, stream>>>(qkv_w, wqkv, 442368);
  cvt_kernel<<<576, 256, 0, stream>>>(proj_w, wproj, 147456);
  cvt_kernel<<<2304, 256, 0, stream>>>(fc1_w, wfc1, 589824);
  cvt_kernel<<<2304, 256, 0, stream>>>(fc2_w, wfc2, 589824);

  // LN1
  ln_kernel<<<4096, 256, 0, stream>>>(x, ln1_g, ln1_b, hbuf);
  // QKV (BN=192: 768 blocks = 3/CU exact)
  gemmW<0, 2304, 768, 192><<<dim3(12, 64), 1024, 0, stream>>>(
      hbuf, wqkv, nullptr, nullptr, nullptr, nullptr, qb, kb, vtb);
  // attention (1-D grid, head-clustered XCD remap)
  attn_kernel<<<dim3(1536), 256, 0, stream>>>(qb, kb, vtb, ob);
  // proj + residual -> x1 (in d_out)  (BN=192: 256 blocks = 1/CU exact)
  gemmW<1, 768, 768, 192><<<dim3(4, 64), 1024, 0, stream>>>(
      ob, wproj, out, proj_b, x, nullptr, nullptr, nullptr, nullptr);
  // LN2
  ln_kernel<<<4096, 256, 0, stream>>>(out, ln2_g, ln2_b, hbuf);
  // FC1 + gelu (BN=256: 768 blocks = 3/CU exact)
  gemmW<2, 3072, 768, 256><<<dim3(12, 64), 1024, 0, stream>>>(
      hbuf, wfc1, nullptr, fc1_b, nullptr, hid, nullptr, nullptr, nullptr);
  // FC2 + residual -> out (BN=192: 256 blocks = 1/CU exact)
  gemmW<1, 768, 3072, 192><<<dim3(4, 64), 1024, 0, stream>>>(
      hid, wfc2, out, fc2_b, out, nullptr, nullptr, nullptr, nullptr);
}